// Round 2
// baseline (264.789 us; speedup 1.0000x reference)
//
#include <hip/hip_runtime.h>

#define NROWS 8192
#define DIN   64
#define DMID  1024
#define DOUT  64
#define NDOM  4
#define PADROWS 8704   // 8192 + 4*128 upper bound on padded total
#define MAXTILES 68

typedef _Float16 half8 __attribute__((ext_vector_type(8)));
typedef _Float16 half4v __attribute__((ext_vector_type(4)));
typedef float floatx4 __attribute__((ext_vector_type(4)));

__device__ __forceinline__ void gload16(const void* g, void* l) {
  __builtin_amdgcn_global_load_lds((const __attribute__((address_space(1))) void*)g,
                                   (__attribute__((address_space(3))) void*)l, 16, 0, 0);
}

// ---------------- conversion kernels ----------------

__global__ void cast_f32_to_f16(const float* __restrict__ src, _Float16* __restrict__ dst, int n4) {
  int i = blockIdx.x * blockDim.x + threadIdx.x;
  if (i < n4) {
    float4 v = reinterpret_cast<const float4*>(src)[i];
    half4v o;
    o[0] = (_Float16)v.x; o[1] = (_Float16)v.y; o[2] = (_Float16)v.z; o[3] = (_Float16)v.w;
    reinterpret_cast<half4v*>(dst)[i] = o;
  }
}

// src: [batch][R][C] fp32  ->  dst: [batch][C][R] fp16   (R,C multiples of 64)
__global__ void transpose_cast(const float* __restrict__ src, _Float16* __restrict__ dst,
                               int R, int C) {
  const int b = blockIdx.z;
  src += (size_t)b * R * C;
  dst += (size_t)b * R * C;
  const int c0 = blockIdx.x * 64;
  const int r0 = blockIdx.y * 64;
  __shared__ float tile[64][65];
  const int t = threadIdx.x;
  const int x = t & 63;
  const int y4 = t >> 6;   // 0..3
#pragma unroll
  for (int i = 0; i < 16; ++i) {
    int r = y4 * 16 + i;
    tile[r][x] = src[(size_t)(r0 + r) * C + (c0 + x)];
  }
  __syncthreads();
#pragma unroll
  for (int i = 0; i < 16; ++i) {
    int c = y4 * 16 + i;
    dst[(size_t)(c0 + c) * R + (r0 + x)] = (_Float16)tile[x][c];
  }
}

// ---------------- routing setup ----------------
// meta[0]=T ; meta[8+t]=domain ; meta[80+t]=tile base row (sorted space) ; meta[160+t]=valid rows
__global__ void setup_kernel(const int* __restrict__ domains, int* __restrict__ meta,
                             int* __restrict__ sortpos, int* __restrict__ invperm) {
  __shared__ int cnt[NDOM];
  __shared__ int cur[NDOM];
  const int t = threadIdx.x;
  if (t < NDOM) cnt[t] = 0;
  __syncthreads();
  for (int i = t; i < NROWS; i += blockDim.x)
    atomicAdd(&cnt[domains[i]], 1);
  __syncthreads();
  if (t == 0) {
    int off = 0, T = 0;
    for (int d = 0; d < NDOM; ++d) {
      cur[d] = off;
      int c = cnt[d];
      int nt = (c + 127) >> 7;
      for (int k = 0; k < nt; ++k) {
        meta[8 + T]   = d;
        meta[80 + T]  = off + k * 128;
        int rem = c - k * 128;
        meta[160 + T] = rem > 128 ? 128 : rem;
        ++T;
      }
      off += nt * 128;
    }
    meta[0] = T;
  }
  __syncthreads();
  for (int i = t; i < NROWS; i += blockDim.x) {
    int d = domains[i];
    int p = atomicAdd(&cur[d], 1);
    sortpos[i] = p;
    invperm[p] = i;
  }
}

// ---------------- small GEMM (layer 1 K=64, final layer N=64) ----------------
// (unchanged proven kernel from R1)
template<int BN, int NKT, bool RELU, int IN_MODE, int OUT_MODE>
__global__ __launch_bounds__(256, 2)
void gemm_f16(const _Float16* __restrict__ A, const _Float16* __restrict__ Bt,
              const float* __restrict__ bias,
              _Float16* __restrict__ Ch, float* __restrict__ Cf,
              const int* __restrict__ meta, const int* __restrict__ sortpos,
              const int* __restrict__ invperm, int ldC) {
  constexpr int BM = 128, BK = 64;
  constexpr int K = NKT * BK;
  constexpr int NFN = BN / 32;
  const int tid = threadIdx.x;
  const int lane = tid & 63, wv = tid >> 6;
  const int lr = lane & 15, lk = lane >> 4;
  const int wr = wv >> 1, wc = wv & 1;

  int rowbase, valid = BM;
  if constexpr (IN_MODE == 1) {
    const int T = meta[0];
    if ((int)blockIdx.y >= T) return;
    const int dom = meta[8 + blockIdx.y];
    rowbase = meta[80 + blockIdx.y];
    valid   = meta[160 + blockIdx.y];
    Bt   += (size_t)dom * ldC * K;
    bias += (size_t)dom * ldC;
  } else {
    rowbase = blockIdx.y * BM;
  }
  const int n0 = blockIdx.x * BN;

  __shared__ __align__(16) unsigned char sA[BM * BK * 2];
  __shared__ __align__(16) unsigned char sB[BN * BK * 2];

  floatx4 acc[4][NFN];
#pragma unroll
  for (int i = 0; i < 4; ++i)
#pragma unroll
    for (int j = 0; j < NFN; ++j)
      acc[i][j] = (floatx4){0.f, 0.f, 0.f, 0.f};

  const unsigned char* Ab = (const unsigned char*)A + (size_t)rowbase * K * 2;
  const unsigned char* Bb = (const unsigned char*)Bt + (size_t)n0 * K * 2;

  for (int kt = 0; kt < NKT; ++kt) {
    const int kbyte0 = kt * BK * 2;
#pragma unroll
    for (int i = 0; i < 4; ++i) {
      int lo = (wv * 4 + i) * 1024 + lane * 16;
      int row = lo >> 7;
      int kb = lo & 127;
      int gkb = kb ^ ((row & 7) << 4);
      gload16(Ab + (size_t)row * (K * 2) + kbyte0 + gkb, sA + lo);
    }
#pragma unroll
    for (int i = 0; i < BN / 32; ++i) {
      int lo = (wv * (BN / 32) + i) * 1024 + lane * 16;
      int row = lo >> 7;
      int kb = lo & 127;
      int gkb = kb ^ ((row & 7) << 4);
      gload16(Bb + (size_t)row * (K * 2) + kbyte0 + gkb, sB + lo);
    }
    __syncthreads();

#pragma unroll
    for (int kk = 0; kk < 2; ++kk) {
      half8 af[4], bf[NFN];
#pragma unroll
      for (int fm = 0; fm < 4; ++fm) {
        int row = wr * 64 + fm * 16 + lr;
        int kb = kk * 64 + lk * 16;
        int addr = row * 128 + (kb ^ ((row & 7) << 4));
        af[fm] = *(const half8*)(sA + addr);
      }
#pragma unroll
      for (int fn = 0; fn < NFN; ++fn) {
        int row = wc * (BN / 2) + fn * 16 + lr;
        int kb = kk * 64 + lk * 16;
        int addr = row * 128 + (kb ^ ((row & 7) << 4));
        bf[fn] = *(const half8*)(sB + addr);
      }
#pragma unroll
      for (int fm = 0; fm < 4; ++fm)
#pragma unroll
        for (int fn = 0; fn < NFN; ++fn)
          acc[fm][fn] = __builtin_amdgcn_mfma_f32_16x16x32_f16(af[fm], bf[fn], acc[fm][fn], 0, 0, 0);
    }
    __syncthreads();
  }

  const int colbase = n0 + wc * (BN / 2);
#pragma unroll
  for (int fn = 0; fn < NFN; ++fn) {
    const int col = colbase + fn * 16 + lr;
    const float bv = bias[col];
#pragma unroll
    for (int fm = 0; fm < 4; ++fm) {
      const int rl = wr * 64 + fm * 16 + lk * 4;
#pragma unroll
      for (int r = 0; r < 4; ++r) {
        float v = acc[fm][fn][r] + bv;
        if (RELU) v = v > 0.f ? v : 0.f;
        const int row = rl + r;
        if constexpr (OUT_MODE == 0) {
          Ch[(size_t)(rowbase + row) * ldC + col] = (_Float16)v;
        } else if constexpr (OUT_MODE == 1) {
          const int orow = sortpos[rowbase + row];
          Ch[(size_t)orow * ldC + col] = (_Float16)v;
        } else {
          if (row < valid) {
            const int orow = invperm[rowbase + row];
            Cf[(size_t)orow * ldC + col] = v;
          }
        }
      }
    }
  }
}

// ---------------- big pipelined GEMM (K=1024 layers) ----------------
// BM=128 rows, BN cols, 512 threads = 8 waves (2 row-groups x 4 col-groups),
// per-wave 64 x BN/4 output. 2-slot LDS double buffer, counted vmcnt (T4),
// prefetch-at-top (T3), XOR-swizzled LDS (T2), setprio around MFMA (T5).
template<int BN, bool RELU, int IN_MODE, int OUT_MODE>
__global__ __launch_bounds__(512, 2)
void gemm8(const _Float16* __restrict__ A, const _Float16* __restrict__ Bt,
           const float* __restrict__ bias, _Float16* __restrict__ Ch,
           const int* __restrict__ meta, const int* __restrict__ sortpos) {
  constexpr int BM = 128, BK = 64, K = DMID, NKT = K / BK;   // NKT = 16
  constexpr int NFN = BN / 64;            // 4 (BN=256) or 2 (BN=128)
  constexpr int BLOADS = BN / 64;         // B stage ops per thread per K-tile
  constexpr int SLOT = (BM + BN) * BK * 2;
  extern __shared__ __align__(16) unsigned char lds[];

  const int tid = threadIdx.x;
  const int lane = tid & 63;
  const int wv = tid >> 6;
  const int lr = lane & 15, lk = lane >> 4;
  const int wr = wv >> 2, wc = wv & 3;

  int rowbase;
  const _Float16* Bt2 = Bt;
  const float* bias2 = bias;
  if constexpr (IN_MODE == 1) {
    if ((int)blockIdx.y >= meta[0]) return;
    const int dom = meta[8 + blockIdx.y];
    rowbase = meta[80 + blockIdx.y];
    Bt2   += (size_t)dom * DMID * K;
    bias2 += (size_t)dom * DMID;
  } else {
    rowbase = blockIdx.y * BM;
  }
  const int n0 = blockIdx.x * BN;

  const unsigned char* Ab = (const unsigned char*)A + (size_t)rowbase * (K * 2);
  const unsigned char* Bb = (const unsigned char*)Bt2 + (size_t)n0 * (K * 2);

  floatx4 acc[4][NFN];
#pragma unroll
  for (int i = 0; i < 4; ++i)
#pragma unroll
    for (int j = 0; j < NFN; ++j)
      acc[i][j] = (floatx4){0.f, 0.f, 0.f, 0.f};

  auto stage = [&](int kt, int slot) {
    unsigned char* sA = lds + slot * SLOT;
    unsigned char* sB = sA + BM * BK * 2;
    const int kbyte0 = kt * (BK * 2);
#pragma unroll
    for (int i = 0; i < 2; ++i) {
      int lo = i * 8192 + tid * 16;
      int row = lo >> 7, kb = lo & 127;
      gload16(Ab + (size_t)row * (K * 2) + kbyte0 + (kb ^ ((row & 7) << 4)), sA + lo);
    }
#pragma unroll
    for (int i = 0; i < BLOADS; ++i) {
      int lo = i * 8192 + tid * 16;
      int row = lo >> 7, kb = lo & 127;
      gload16(Bb + (size_t)row * (K * 2) + kbyte0 + (kb ^ ((row & 7) << 4)), sB + lo);
    }
  };

  stage(0, 0);
  for (int t = 0; t < NKT; ++t) {
    if (t + 1 < NKT) {
      stage(t + 1, (t + 1) & 1);
      // wait for tile t only (oldest UNIT loads); tile t+1 stays in flight
      if constexpr (BLOADS == 4) asm volatile("s_waitcnt vmcnt(6)" ::: "memory");
      else                       asm volatile("s_waitcnt vmcnt(4)" ::: "memory");
    } else {
      asm volatile("s_waitcnt vmcnt(0)" ::: "memory");
    }
    __builtin_amdgcn_s_barrier();
    asm volatile("" ::: "memory");

    const unsigned char* sA = lds + (t & 1) * SLOT;
    const unsigned char* sB = sA + BM * BK * 2;
    half8 af[4][2];
    half8 bf[NFN][2];
#pragma unroll
    for (int fm = 0; fm < 4; ++fm) {
      const int row = wr * 64 + fm * 16 + lr;
#pragma unroll
      for (int kk = 0; kk < 2; ++kk) {
        const int kb = kk * 64 + lk * 16;
        af[fm][kk] = *(const half8*)(sA + row * 128 + (kb ^ ((row & 7) << 4)));
      }
    }
#pragma unroll
    for (int fn = 0; fn < NFN; ++fn) {
      const int row = wc * (BN / 4) + fn * 16 + lr;
#pragma unroll
      for (int kk = 0; kk < 2; ++kk) {
        const int kb = kk * 64 + lk * 16;
        bf[fn][kk] = *(const half8*)(sB + row * 128 + (kb ^ ((row & 7) << 4)));
      }
    }
    __builtin_amdgcn_s_setprio(1);
#pragma unroll
    for (int kk = 0; kk < 2; ++kk)
#pragma unroll
      for (int fm = 0; fm < 4; ++fm)
#pragma unroll
        for (int fn = 0; fn < NFN; ++fn)
          acc[fm][fn] = __builtin_amdgcn_mfma_f32_16x16x32_f16(af[fm][kk], bf[fn][kk], acc[fm][fn], 0, 0, 0);
    __builtin_amdgcn_s_setprio(0);
    asm volatile("" ::: "memory");
    __builtin_amdgcn_s_barrier();
  }

  // epilogue: bias (+relu), fp16 store (direct or sorted-scatter)
  const int colbase = n0 + wc * (BN / 4);
#pragma unroll
  for (int fn = 0; fn < NFN; ++fn) {
    const int col = colbase + fn * 16 + lr;
    const float bv = bias2[col];
#pragma unroll
    for (int fm = 0; fm < 4; ++fm) {
      const int rl = wr * 64 + fm * 16 + lk * 4;
#pragma unroll
      for (int r = 0; r < 4; ++r) {
        float v = acc[fm][fn][r] + bv;
        if (RELU) v = v > 0.f ? v : 0.f;
        const int row = rowbase + rl + r;
        if constexpr (OUT_MODE == 0) {
          Ch[(size_t)row * DMID + col] = (_Float16)v;
        } else {
          const int orow = sortpos[row];
          Ch[(size_t)orow * DMID + col] = (_Float16)v;
        }
      }
    }
  }
}

// ---------------- launch ----------------

extern "C" void kernel_launch(void* const* d_in, const int* in_sizes, int n_in,
                              void* d_out, int out_size, void* d_ws, size_t ws_size,
                              hipStream_t stream) {
  const float* X   = (const float*)d_in[0];
  const int* domains = (const int*)d_in[1];
  const float* W1  = (const float*)d_in[2];
  const float* b1  = (const float*)d_in[3];
  const float* W2  = (const float*)d_in[4];
  const float* b2  = (const float*)d_in[5];
  const float* W3  = (const float*)d_in[6];
  const float* b3  = (const float*)d_in[7];
  const float* W4  = (const float*)d_in[8];
  const float* b4  = (const float*)d_in[9];
  const float* BW1 = (const float*)d_in[10];
  const float* Bb1 = (const float*)d_in[11];
  const float* BW2 = (const float*)d_in[12];
  const float* Bb2 = (const float*)d_in[13];
  const float* BW3 = (const float*)d_in[14];
  const float* Bb3 = (const float*)d_in[15];
  const float* BW4 = (const float*)d_in[16];
  const float* Bb4 = (const float*)d_in[17];
  float* out = (float*)d_out;

  char* base = (char*)d_ws;
  size_t off = 0;
  auto alloc = [&](size_t bytes) -> void* {
    void* p = base + off;
    off = (off + bytes + 255) & ~(size_t)255;
    return p;
  };
  _Float16* Xh   = (_Float16*)alloc((size_t)NROWS * DIN * 2);
  _Float16* W1t  = (_Float16*)alloc((size_t)DMID * DIN * 2);
  _Float16* W2t  = (_Float16*)alloc((size_t)DMID * DMID * 2);
  _Float16* W3t  = (_Float16*)alloc((size_t)DMID * DMID * 2);
  _Float16* W4t  = (_Float16*)alloc((size_t)DMID * DMID * 2);
  _Float16* BW1t = (_Float16*)alloc((size_t)NDOM * DMID * DMID * 2);
  _Float16* BW2t = (_Float16*)alloc((size_t)NDOM * DMID * DMID * 2);
  _Float16* BW3t = (_Float16*)alloc((size_t)NDOM * DMID * DMID * 2);
  _Float16* BW4t = (_Float16*)alloc((size_t)NDOM * DOUT * DMID * 2);
  _Float16* bufA = (_Float16*)alloc((size_t)NROWS * DMID * 2);
  _Float16* bufS0= (_Float16*)alloc((size_t)PADROWS * DMID * 2);
  _Float16* bufS1= (_Float16*)alloc((size_t)PADROWS * DMID * 2);
  int* sortpos   = (int*)alloc((size_t)NROWS * 4);
  int* invperm   = (int*)alloc((size_t)PADROWS * 4);
  int* meta      = (int*)alloc(1024 * 4);

  // conversions
  cast_f32_to_f16<<<dim3((NROWS * DIN / 4) / 256), 256, 0, stream>>>(X, Xh, NROWS * DIN / 4);
  transpose_cast<<<dim3(DMID / 64, DIN / 64, 1),  256, 0, stream>>>(W1, W1t, DIN, DMID);
  transpose_cast<<<dim3(DMID / 64, DMID / 64, 1), 256, 0, stream>>>(W2, W2t, DMID, DMID);
  transpose_cast<<<dim3(DMID / 64, DMID / 64, 1), 256, 0, stream>>>(W3, W3t, DMID, DMID);
  transpose_cast<<<dim3(DMID / 64, DMID / 64, 1), 256, 0, stream>>>(W4, W4t, DMID, DMID);
  transpose_cast<<<dim3(DMID / 64, DMID / 64, NDOM), 256, 0, stream>>>(BW1, BW1t, DMID, DMID);
  transpose_cast<<<dim3(DMID / 64, DMID / 64, NDOM), 256, 0, stream>>>(BW2, BW2t, DMID, DMID);
  transpose_cast<<<dim3(DMID / 64, DMID / 64, NDOM), 256, 0, stream>>>(BW3, BW3t, DMID, DMID);
  transpose_cast<<<dim3(DOUT / 64, DMID / 64, NDOM), 256, 0, stream>>>(BW4, BW4t, DMID, DOUT);

  // routing (no memset: pad rows carry row-local finite garbage, masked at final scatter)
  setup_kernel<<<1, 256, 0, stream>>>(domains, meta, sortpos, invperm);

  // layer 1 (K=64): proven small kernel
  gemm_f16<128, 1,  true, 0, 0><<<dim3(DMID / 128, NROWS / 128), 256, 0, stream>>>(
      Xh, W1t, b1, bufA, nullptr, nullptr, nullptr, nullptr, DMID);

  // big K=1024 layers: pipelined kernel; prefer BN=256 (96KB dyn LDS), fall back to BN=128
  int dyn_ok = 1;
  if (hipFuncSetAttribute((const void*)gemm8<256, true, 0, 0>,
                          hipFuncAttributeMaxDynamicSharedMemorySize, 98304) != hipSuccess) dyn_ok = 0;
  if (hipFuncSetAttribute((const void*)gemm8<256, true, 0, 1>,
                          hipFuncAttributeMaxDynamicSharedMemorySize, 98304) != hipSuccess) dyn_ok = 0;
  if (hipFuncSetAttribute((const void*)gemm8<256, true, 1, 0>,
                          hipFuncAttributeMaxDynamicSharedMemorySize, 98304) != hipSuccess) dyn_ok = 0;

  if (dyn_ok) {
    constexpr int SMEM = (128 + 256) * 64 * 2 * 2;   // 98304
    gemm8<256, true, 0, 0><<<dim3(DMID / 256, NROWS / 128), 512, SMEM, stream>>>(
        bufA, W2t, b2, bufS1, nullptr, nullptr);
    gemm8<256, true, 0, 0><<<dim3(DMID / 256, NROWS / 128), 512, SMEM, stream>>>(
        bufS1, W3t, b3, bufA, nullptr, nullptr);
    gemm8<256, true, 0, 1><<<dim3(DMID / 256, NROWS / 128), 512, SMEM, stream>>>(
        bufA, W4t, b4, bufS0, nullptr, sortpos);
    gemm8<256, true, 1, 0><<<dim3(DMID / 256, MAXTILES), 512, SMEM, stream>>>(
        bufS0, BW1t, Bb1, bufS1, meta, nullptr);
    gemm8<256, true, 1, 0><<<dim3(DMID / 256, MAXTILES), 512, SMEM, stream>>>(
        bufS1, BW2t, Bb2, bufS0, meta, nullptr);
    gemm8<256, true, 1, 0><<<dim3(DMID / 256, MAXTILES), 512, SMEM, stream>>>(
        bufS0, BW3t, Bb3, bufS1, meta, nullptr);
  } else {
    (void)hipFuncSetAttribute((const void*)gemm8<128, true, 0, 0>,
                              hipFuncAttributeMaxDynamicSharedMemorySize, 65536);
    (void)hipFuncSetAttribute((const void*)gemm8<128, true, 0, 1>,
                              hipFuncAttributeMaxDynamicSharedMemorySize, 65536);
    (void)hipFuncSetAttribute((const void*)gemm8<128, true, 1, 0>,
                              hipFuncAttributeMaxDynamicSharedMemorySize, 65536);
    constexpr int SMEM = (128 + 128) * 64 * 2 * 2;   // 65536
    gemm8<128, true, 0, 0><<<dim3(DMID / 128, NROWS / 128), 512, SMEM, stream>>>(
        bufA, W2t, b2, bufS1, nullptr, nullptr);
    gemm8<128, true, 0, 0><<<dim3(DMID / 128, NROWS / 128), 512, SMEM, stream>>>(
        bufS1, W3t, b3, bufA, nullptr, nullptr);
    gemm8<128, true, 0, 1><<<dim3(DMID / 128, NROWS / 128), 512, SMEM, stream>>>(
        bufA, W4t, b4, bufS0, nullptr, sortpos);
    gemm8<128, true, 1, 0><<<dim3(DMID / 128, MAXTILES), 512, SMEM, stream>>>(
        bufS0, BW1t, Bb1, bufS1, meta, nullptr);
    gemm8<128, true, 1, 0><<<dim3(DMID / 128, MAXTILES), 512, SMEM, stream>>>(
        bufS1, BW2t, Bb2, bufS0, meta, nullptr);
    gemm8<128, true, 1, 0><<<dim3(DMID / 128, MAXTILES), 512, SMEM, stream>>>(
        bufS0, BW3t, Bb3, bufS1, meta, nullptr);
  }

  // final layer: fp32 scatter to d_out, no relu (proven small kernel)
  gemm_f16<64, 16, false, 1, 2><<<dim3(1, MAXTILES), 256, 0, stream>>>(
      bufS1, BW4t, Bb4, nullptr, out, meta, nullptr, invperm, DOUT);
}

// Round 3
// 243.372 us; speedup vs baseline: 1.0880x; 1.0880x over previous
//
#include <hip/hip_runtime.h>

#define NROWS 8192
#define DIN   64
#define DMID  1024
#define DOUT  64
#define NDOM  4
#define PADROWS  8960    // 35 tiles * 256
#define MAXT256  35
#define MAXT128  68

typedef _Float16 half8 __attribute__((ext_vector_type(8)));
typedef _Float16 half4v __attribute__((ext_vector_type(4)));
typedef float floatx4 __attribute__((ext_vector_type(4)));

__device__ __forceinline__ void gload16(const void* g, void* l) {
  __builtin_amdgcn_global_load_lds((const __attribute__((address_space(1))) void*)g,
                                   (__attribute__((address_space(3))) void*)l, 16, 0, 0);
}

#define FENCE asm volatile("" ::: "memory")
#define BAR() do { FENCE; __builtin_amdgcn_s_barrier(); FENCE; } while (0)

// ---------------- conversion kernels ----------------

__global__ void cast_f32_to_f16(const float* __restrict__ src, _Float16* __restrict__ dst, int n4) {
  int i = blockIdx.x * blockDim.x + threadIdx.x;
  if (i < n4) {
    float4 v = reinterpret_cast<const float4*>(src)[i];
    half4v o;
    o[0] = (_Float16)v.x; o[1] = (_Float16)v.y; o[2] = (_Float16)v.z; o[3] = (_Float16)v.w;
    reinterpret_cast<half4v*>(dst)[i] = o;
  }
}

// src: [batch][R][C] fp32  ->  dst: [batch][C][R] fp16   (R,C multiples of 64)
__global__ void transpose_cast(const float* __restrict__ src, _Float16* __restrict__ dst,
                               int R, int C) {
  const int b = blockIdx.z;
  src += (size_t)b * R * C;
  dst += (size_t)b * R * C;
  const int c0 = blockIdx.x * 64;
  const int r0 = blockIdx.y * 64;
  __shared__ float tile[64][65];
  const int t = threadIdx.x;
  const int x = t & 63;
  const int y4 = t >> 6;
#pragma unroll
  for (int i = 0; i < 16; ++i) {
    int r = y4 * 16 + i;
    tile[r][x] = src[(size_t)(r0 + r) * C + (c0 + x)];
  }
  __syncthreads();
#pragma unroll
  for (int i = 0; i < 16; ++i) {
    int c = y4 * 16 + i;
    dst[(size_t)(c0 + c) * R + (r0 + x)] = (_Float16)tile[x][c];
  }
}

// ---------------- routing setup ----------------
// meta   (256-gran): [0]=T,  [8+t]=dom, [80+t]=base
// meta+512 (128-gran): [0]=T2, [8+t]=dom, [80+t]=base, [160+t]=valid
__global__ void setup_kernel(const int* __restrict__ domains, int* __restrict__ meta,
                             int* __restrict__ sortpos, int* __restrict__ invperm) {
  __shared__ int cnt[NDOM];
  __shared__ int cur[NDOM];
  const int t = threadIdx.x;
  if (t < NDOM) cnt[t] = 0;
  __syncthreads();
  for (int i = t; i < NROWS; i += blockDim.x)
    atomicAdd(&cnt[domains[i]], 1);
  __syncthreads();
  if (t == 0) {
    int* m2 = meta + 512;
    int off = 0, T = 0, T2 = 0;
    for (int d = 0; d < NDOM; ++d) {
      cur[d] = off;
      int c = cnt[d];
      int nt = (c + 255) >> 8;
      for (int k = 0; k < nt; ++k) {
        meta[8 + T]  = d;
        meta[80 + T] = off + k * 256;
        ++T;
      }
      int nt2 = (c + 127) >> 7;
      for (int k = 0; k < nt2; ++k) {
        m2[8 + T2]   = d;
        m2[80 + T2]  = off + k * 128;
        int rem = c - k * 128;
        m2[160 + T2] = rem > 128 ? 128 : rem;
        ++T2;
      }
      off += nt * 256;
    }
    meta[0] = T;
    m2[0]   = T2;
  }
  __syncthreads();
  for (int i = t; i < NROWS; i += blockDim.x) {
    int d = domains[i];
    int p = atomicAdd(&cur[d], 1);
    sortpos[i] = p;
    invperm[p] = i;
  }
}

// ---------------- small GEMM (layer 1 K=64, final layer N=64; also fallback) ----------------
template<int BN, int NKT, bool RELU, int IN_MODE, int OUT_MODE>
__global__ __launch_bounds__(256, 2)
void gemm_f16(const _Float16* __restrict__ A, const _Float16* __restrict__ Bt,
              const float* __restrict__ bias,
              _Float16* __restrict__ Ch, float* __restrict__ Cf,
              const int* __restrict__ meta, const int* __restrict__ sortpos,
              const int* __restrict__ invperm, int ldC) {
  constexpr int BM = 128, BK = 64;
  constexpr int K = NKT * BK;
  constexpr int NFN = BN / 32;
  const int tid = threadIdx.x;
  const int lane = tid & 63, wv = tid >> 6;
  const int lr = lane & 15, lk = lane >> 4;
  const int wr = wv >> 1, wc = wv & 1;

  int rowbase, valid = BM;
  if constexpr (IN_MODE == 1) {
    const int T = meta[0];
    if ((int)blockIdx.y >= T) return;
    const int dom = meta[8 + blockIdx.y];
    rowbase = meta[80 + blockIdx.y];
    valid   = meta[160 + blockIdx.y];
    Bt   += (size_t)dom * ldC * K;
    bias += (size_t)dom * ldC;
  } else {
    rowbase = blockIdx.y * BM;
  }
  const int n0 = blockIdx.x * BN;

  __shared__ __align__(16) unsigned char sA[BM * BK * 2];
  __shared__ __align__(16) unsigned char sB[BN * BK * 2];

  floatx4 acc[4][NFN];
#pragma unroll
  for (int i = 0; i < 4; ++i)
#pragma unroll
    for (int j = 0; j < NFN; ++j)
      acc[i][j] = (floatx4){0.f, 0.f, 0.f, 0.f};

  const unsigned char* Ab = (const unsigned char*)A + (size_t)rowbase * K * 2;
  const unsigned char* Bb = (const unsigned char*)Bt + (size_t)n0 * K * 2;

  for (int kt = 0; kt < NKT; ++kt) {
    const int kbyte0 = kt * BK * 2;
#pragma unroll
    for (int i = 0; i < 4; ++i) {
      int lo = (wv * 4 + i) * 1024 + lane * 16;
      int row = lo >> 7;
      int kb = lo & 127;
      int gkb = kb ^ ((row & 7) << 4);
      gload16(Ab + (size_t)row * (K * 2) + kbyte0 + gkb, sA + lo);
    }
#pragma unroll
    for (int i = 0; i < BN / 32; ++i) {
      int lo = (wv * (BN / 32) + i) * 1024 + lane * 16;
      int row = lo >> 7;
      int kb = lo & 127;
      int gkb = kb ^ ((row & 7) << 4);
      gload16(Bb + (size_t)row * (K * 2) + kbyte0 + gkb, sB + lo);
    }
    __syncthreads();

#pragma unroll
    for (int kk = 0; kk < 2; ++kk) {
      half8 af[4], bf[NFN];
#pragma unroll
      for (int fm = 0; fm < 4; ++fm) {
        int row = wr * 64 + fm * 16 + lr;
        int kb = kk * 64 + lk * 16;
        int addr = row * 128 + (kb ^ ((row & 7) << 4));
        af[fm] = *(const half8*)(sA + addr);
      }
#pragma unroll
      for (int fn = 0; fn < NFN; ++fn) {
        int row = wc * (BN / 2) + fn * 16 + lr;
        int kb = kk * 64 + lk * 16;
        int addr = row * 128 + (kb ^ ((row & 7) << 4));
        bf[fn] = *(const half8*)(sB + addr);
      }
#pragma unroll
      for (int fm = 0; fm < 4; ++fm)
#pragma unroll
        for (int fn = 0; fn < NFN; ++fn)
          acc[fm][fn] = __builtin_amdgcn_mfma_f32_16x16x32_f16(af[fm], bf[fn], acc[fm][fn], 0, 0, 0);
    }
    __syncthreads();
  }

  const int colbase = n0 + wc * (BN / 2);
#pragma unroll
  for (int fn = 0; fn < NFN; ++fn) {
    const int col = colbase + fn * 16 + lr;
    const float bv = bias[col];
#pragma unroll
    for (int fm = 0; fm < 4; ++fm) {
      const int rl = wr * 64 + fm * 16 + lk * 4;
#pragma unroll
      for (int r = 0; r < 4; ++r) {
        float v = acc[fm][fn][r] + bv;
        if (RELU) v = v > 0.f ? v : 0.f;
        const int row = rl + r;
        if constexpr (OUT_MODE == 0) {
          Ch[(size_t)(rowbase + row) * ldC + col] = (_Float16)v;
        } else if constexpr (OUT_MODE == 1) {
          const int orow = sortpos[rowbase + row];
          Ch[(size_t)orow * ldC + col] = (_Float16)v;
        } else {
          if (row < valid) {
            const int orow = invperm[rowbase + row];
            Cf[(size_t)orow * ldC + col] = v;
          }
        }
      }
    }
  }
}

// ---------------- big 8-phase GEMM (K=1024 layers), m201-style ----------------
// BM=256 x BN=128 x BK=64, 512 thr = 8 waves (4M x 2N), per-wave 64x64.
// LDS ring: A = 4 half-slots (128 rows x 64K = 16KB each), slot=(t&1)*2+half;
//           B = 2 slots (128 x 64K), slot=(t&1).  Total 96KB (dynamic).
// Per K-tile: 4 phases {ds_read subtile | stage 1 unit | bar | 8 MFMA | bar},
// one counted vmcnt(4) per K-tile placed BEFORE phase-4's closing barrier.
template<int IN_MODE, int OUT_MODE>
__global__ __launch_bounds__(512, 2)
void gemm_big(const _Float16* __restrict__ A, const _Float16* __restrict__ Bt,
              const float* __restrict__ bias, _Float16* __restrict__ Ch,
              const int* __restrict__ meta, const int* __restrict__ sortpos,
              int chunk) {
  constexpr int K = DMID, NT = K / 64;   // 16 K-tiles
  extern __shared__ __align__(16) unsigned char lds[];   // 96KB

  const int tid  = threadIdx.x;
  const int lane = tid & 63;
  const int wv   = tid >> 6;
  const int lr = lane & 15, lk = lane >> 4;
  const int wr = wv >> 1, wc = wv & 1;

  // XCD-aware bijective swizzle (grid = 8*chunk)
  const int bid = blockIdx.x;
  const int l  = (bid & 7) * chunk + (bid >> 3);
  const int by = l >> 3, bx = l & 7;

  int rowbase;
  const _Float16* Bt2 = Bt;
  const float* bias2 = bias;
  if constexpr (IN_MODE == 1) {
    if (by >= meta[0]) return;
    const int dom = meta[8 + by];
    rowbase = meta[80 + by];
    Bt2   += (size_t)dom * DMID * K;
    bias2 += (size_t)dom * DMID;
  } else {
    rowbase = by * 256;
  }
  const int n0 = bx * 128;

  const unsigned char* Ab = (const unsigned char*)A + (size_t)rowbase * (K * 2);
  const unsigned char* Bb = (const unsigned char*)Bt2 + (size_t)n0 * (K * 2);

  floatx4 acc[4][4];
#pragma unroll
  for (int i = 0; i < 4; ++i)
#pragma unroll
    for (int j = 0; j < 4; ++j)
      acc[i][j] = (floatx4){0.f, 0.f, 0.f, 0.f};

  auto stageA = [&](int kt, int h) {
    unsigned char* dst = lds + ((((kt & 1) << 1) + h) * 16384);
    const unsigned char* src = Ab + (size_t)(h * 128) * (K * 2) + kt * 128;
#pragma unroll
    for (int i = 0; i < 2; ++i) {
      int lo = i * 8192 + tid * 16;
      int r = lo >> 7, kb = lo & 127;
      gload16(src + (size_t)r * (K * 2) + (kb ^ ((r & 7) << 4)), dst + lo);
    }
  };
  auto stageB = [&](int kt) {
    unsigned char* dst = lds + 65536 + (kt & 1) * 16384;
    const unsigned char* src = Bb + kt * 128;
#pragma unroll
    for (int i = 0; i < 2; ++i) {
      int lo = i * 8192 + tid * 16;
      int r = lo >> 7, kb = lo & 127;
      gload16(src + (size_t)r * (K * 2) + (kb ^ ((r & 7) << 4)), dst + lo);
    }
  };
  auto readA = [&](int t, int fm, int kk) -> half8 {
    int row = wr * 64 + fm * 16 + lr;        // 0..255
    int h = row >> 7, r = row & 127;
    const unsigned char* base = lds + ((((t & 1) << 1) + h) * 16384);
    int kb = kk * 64 + lk * 16;
    return *(const half8*)(base + r * 128 + (kb ^ ((r & 7) << 4)));
  };
  auto readB = [&](int t, int fn, int kk) -> half8 {
    int row = wc * 64 + fn * 16 + lr;        // 0..127
    const unsigned char* base = lds + 65536 + (t & 1) * 16384;
    int kb = kk * 64 + lk * 16;
    return *(const half8*)(base + row * 128 + (kb ^ ((row & 7) << 4)));
  };

  half8 af[4][2], bf[4][2];

  // prologue: t0 fully + t1 A-halves; wait own portion of t0; publish via barrier
  stageA(0, 0); stageA(0, 1); stageB(0); stageA(1, 0); stageA(1, 1);
  asm volatile("s_waitcnt vmcnt(4)" ::: "memory");
  BAR();

#pragma unroll
  for (int t = 0; t < NT; ++t) {
    // ---- P1: read A fm{0,1}, B fn{0,1}; stage B(t+1) ----
#pragma unroll
    for (int kk = 0; kk < 2; ++kk) {
      af[0][kk] = readA(t, 0, kk); af[1][kk] = readA(t, 1, kk);
      bf[0][kk] = readB(t, 0, kk); bf[1][kk] = readB(t, 1, kk);
    }
    if (t + 1 < NT) stageB(t + 1);
    BAR();
    __builtin_amdgcn_s_setprio(1);
#pragma unroll
    for (int kk = 0; kk < 2; ++kk)
#pragma unroll
      for (int fm = 0; fm < 2; ++fm)
#pragma unroll
        for (int fn = 0; fn < 2; ++fn)
          acc[fm][fn] = __builtin_amdgcn_mfma_f32_16x16x32_f16(af[fm][kk], bf[fn][kk], acc[fm][fn], 0, 0, 0);
    __builtin_amdgcn_s_setprio(0);
    BAR();
    // ---- P2: read A fm{2,3} ----
#pragma unroll
    for (int kk = 0; kk < 2; ++kk) {
      af[2][kk] = readA(t, 2, kk); af[3][kk] = readA(t, 3, kk);
    }
    BAR();
    __builtin_amdgcn_s_setprio(1);
#pragma unroll
    for (int kk = 0; kk < 2; ++kk)
#pragma unroll
      for (int fm = 2; fm < 4; ++fm)
#pragma unroll
        for (int fn = 0; fn < 2; ++fn)
          acc[fm][fn] = __builtin_amdgcn_mfma_f32_16x16x32_f16(af[fm][kk], bf[fn][kk], acc[fm][fn], 0, 0, 0);
    __builtin_amdgcn_s_setprio(0);
    BAR();
    // ---- P3: read B fn{2,3}; stage A(t+2, half0) (A slots of tile t freed at P2 barrier) ----
#pragma unroll
    for (int kk = 0; kk < 2; ++kk) {
      bf[2][kk] = readB(t, 2, kk); bf[3][kk] = readB(t, 3, kk);
    }
    if (t + 2 < NT) stageA(t + 2, 0);
    BAR();
    __builtin_amdgcn_s_setprio(1);
#pragma unroll
    for (int kk = 0; kk < 2; ++kk)
#pragma unroll
      for (int fm = 2; fm < 4; ++fm)
#pragma unroll
        for (int fn = 2; fn < 4; ++fn)
          acc[fm][fn] = __builtin_amdgcn_mfma_f32_16x16x32_f16(af[fm][kk], bf[fn][kk], acc[fm][fn], 0, 0, 0);
    __builtin_amdgcn_s_setprio(0);
    BAR();
    // ---- P4: stage A(t+2, half1); MFMA fm{0,1} x fn{2,3}; counted vmcnt BEFORE closing barrier ----
    if (t + 2 < NT) stageA(t + 2, 1);
    BAR();
    __builtin_amdgcn_s_setprio(1);
#pragma unroll
    for (int kk = 0; kk < 2; ++kk)
#pragma unroll
      for (int fm = 0; fm < 2; ++fm)
#pragma unroll
        for (int fn = 2; fn < 4; ++fn)
          acc[fm][fn] = __builtin_amdgcn_mfma_f32_16x16x32_f16(af[fm][kk], bf[fn][kk], acc[fm][fn], 0, 0, 0);
    __builtin_amdgcn_s_setprio(0);
    if (t + 2 < NT)      asm volatile("s_waitcnt vmcnt(4)" ::: "memory");
    else if (t + 1 < NT) asm volatile("s_waitcnt vmcnt(0)" ::: "memory");
    BAR();
  }

  // epilogue: bias + relu, fp16 store
  const int colbase = n0 + wc * 64;
#pragma unroll
  for (int fn = 0; fn < 4; ++fn) {
    const int col = colbase + fn * 16 + lr;
    const float bv = bias2[col];
#pragma unroll
    for (int fm = 0; fm < 4; ++fm) {
      const int rl = wr * 64 + fm * 16 + lk * 4;
#pragma unroll
      for (int r = 0; r < 4; ++r) {
        float v = acc[fm][fn][r] + bv;
        v = v > 0.f ? v : 0.f;
        const int row = rowbase + rl + r;
        if constexpr (OUT_MODE == 0) {
          Ch[(size_t)row * DMID + col] = (_Float16)v;
        } else {
          const int orow = sortpos[row];
          Ch[(size_t)orow * DMID + col] = (_Float16)v;
        }
      }
    }
  }
}

// ---------------- launch ----------------

extern "C" void kernel_launch(void* const* d_in, const int* in_sizes, int n_in,
                              void* d_out, int out_size, void* d_ws, size_t ws_size,
                              hipStream_t stream) {
  const float* X   = (const float*)d_in[0];
  const int* domains = (const int*)d_in[1];
  const float* W1  = (const float*)d_in[2];
  const float* b1  = (const float*)d_in[3];
  const float* W2  = (const float*)d_in[4];
  const float* b2  = (const float*)d_in[5];
  const float* W3  = (const float*)d_in[6];
  const float* b3  = (const float*)d_in[7];
  const float* W4  = (const float*)d_in[8];
  const float* b4  = (const float*)d_in[9];
  const float* BW1 = (const float*)d_in[10];
  const float* Bb1 = (const float*)d_in[11];
  const float* BW2 = (const float*)d_in[12];
  const float* Bb2 = (const float*)d_in[13];
  const float* BW3 = (const float*)d_in[14];
  const float* Bb3 = (const float*)d_in[15];
  const float* BW4 = (const float*)d_in[16];
  const float* Bb4 = (const float*)d_in[17];
  float* out = (float*)d_out;

  char* base = (char*)d_ws;
  size_t off = 0;
  auto alloc = [&](size_t bytes) -> void* {
    void* p = base + off;
    off = (off + bytes + 255) & ~(size_t)255;
    return p;
  };
  _Float16* Xh   = (_Float16*)alloc((size_t)NROWS * DIN * 2);
  _Float16* W1t  = (_Float16*)alloc((size_t)DMID * DIN * 2);
  _Float16* W2t  = (_Float16*)alloc((size_t)DMID * DMID * 2);
  _Float16* W3t  = (_Float16*)alloc((size_t)DMID * DMID * 2);
  _Float16* W4t  = (_Float16*)alloc((size_t)DMID * DMID * 2);
  _Float16* BW1t = (_Float16*)alloc((size_t)NDOM * DMID * DMID * 2);
  _Float16* BW2t = (_Float16*)alloc((size_t)NDOM * DMID * DMID * 2);
  _Float16* BW3t = (_Float16*)alloc((size_t)NDOM * DMID * DMID * 2);
  _Float16* BW4t = (_Float16*)alloc((size_t)NDOM * DOUT * DMID * 2);
  _Float16* bufA = (_Float16*)alloc((size_t)NROWS * DMID * 2);
  _Float16* bufS0= (_Float16*)alloc((size_t)PADROWS * DMID * 2);
  _Float16* bufS1= (_Float16*)alloc((size_t)PADROWS * DMID * 2);
  int* sortpos   = (int*)alloc((size_t)NROWS * 4);
  int* invperm   = (int*)alloc((size_t)PADROWS * 4);
  int* meta      = (int*)alloc(1024 * 4);
  int* meta2     = meta + 512;

  // conversions
  cast_f32_to_f16<<<dim3((NROWS * DIN / 4) / 256), 256, 0, stream>>>(X, Xh, NROWS * DIN / 4);
  transpose_cast<<<dim3(DMID / 64, DIN / 64, 1),  256, 0, stream>>>(W1, W1t, DIN, DMID);
  transpose_cast<<<dim3(DMID / 64, DMID / 64, 1), 256, 0, stream>>>(W2, W2t, DMID, DMID);
  transpose_cast<<<dim3(DMID / 64, DMID / 64, 1), 256, 0, stream>>>(W3, W3t, DMID, DMID);
  transpose_cast<<<dim3(DMID / 64, DMID / 64, 1), 256, 0, stream>>>(W4, W4t, DMID, DMID);
  transpose_cast<<<dim3(DMID / 64, DMID / 64, NDOM), 256, 0, stream>>>(BW1, BW1t, DMID, DMID);
  transpose_cast<<<dim3(DMID / 64, DMID / 64, NDOM), 256, 0, stream>>>(BW2, BW2t, DMID, DMID);
  transpose_cast<<<dim3(DMID / 64, DMID / 64, NDOM), 256, 0, stream>>>(BW3, BW3t, DMID, DMID);
  transpose_cast<<<dim3(DOUT / 64, DMID / 64, NDOM), 256, 0, stream>>>(BW4, BW4t, DMID, DOUT);

  setup_kernel<<<1, 256, 0, stream>>>(domains, meta, sortpos, invperm);

  // layer 1 (K=64)
  gemm_f16<128, 1, true, 0, 0><<<dim3(DMID / 128, NROWS / 128), 256, 0, stream>>>(
      Xh, W1t, b1, bufA, nullptr, nullptr, nullptr, nullptr, DMID);

  int dyn_ok = 1;
  if (hipFuncSetAttribute((const void*)gemm_big<0, 0>,
                          hipFuncAttributeMaxDynamicSharedMemorySize, 98304) != hipSuccess) dyn_ok = 0;
  if (hipFuncSetAttribute((const void*)gemm_big<0, 1>,
                          hipFuncAttributeMaxDynamicSharedMemorySize, 98304) != hipSuccess) dyn_ok = 0;
  if (hipFuncSetAttribute((const void*)gemm_big<1, 0>,
                          hipFuncAttributeMaxDynamicSharedMemorySize, 98304) != hipSuccess) dyn_ok = 0;

  if (dyn_ok) {
    constexpr int SMEM = 96 * 1024;
    // dense K=1024 layers: grid 256 = 8 col x 32 row tiles, chunk 32
    gemm_big<0, 0><<<256, 512, SMEM, stream>>>(bufA,  W2t, b2, bufS1, nullptr, nullptr, 32);
    gemm_big<0, 0><<<256, 512, SMEM, stream>>>(bufS1, W3t, b3, bufA,  nullptr, nullptr, 32);
    gemm_big<0, 1><<<256, 512, SMEM, stream>>>(bufA,  W4t, b4, bufS0, nullptr, sortpos, 32);
    // branch layers 1-3: grid 280 = 8 x 35, chunk 35
    gemm_big<1, 0><<<280, 512, SMEM, stream>>>(bufS0, BW1t, Bb1, bufS1, meta, nullptr, MAXT256);
    gemm_big<1, 0><<<280, 512, SMEM, stream>>>(bufS1, BW2t, Bb2, bufS0, meta, nullptr, MAXT256);
    gemm_big<1, 0><<<280, 512, SMEM, stream>>>(bufS0, BW3t, Bb3, bufS1, meta, nullptr, MAXT256);
  } else {
    // fallback: proven R1 kernels
    gemm_f16<128, 16, true, 0, 0><<<dim3(DMID / 128, NROWS / 128), 256, 0, stream>>>(
        bufA, W2t, b2, bufS1, nullptr, nullptr, nullptr, nullptr, DMID);
    gemm_f16<128, 16, true, 0, 0><<<dim3(DMID / 128, NROWS / 128), 256, 0, stream>>>(
        bufS1, W3t, b3, bufA, nullptr, nullptr, nullptr, nullptr, DMID);
    gemm_f16<128, 16, true, 0, 1><<<dim3(DMID / 128, NROWS / 128), 256, 0, stream>>>(
        bufA, W4t, b4, bufS0, nullptr, nullptr, sortpos, nullptr, DMID);
    gemm_f16<128, 16, true, 1, 0><<<dim3(DMID / 128, MAXT128), 256, 0, stream>>>(
        bufS0, BW1t, Bb1, bufS1, nullptr, meta2, nullptr, nullptr, DMID);
    gemm_f16<128, 16, true, 1, 0><<<dim3(DMID / 128, MAXT128), 256, 0, stream>>>(
        bufS1, BW2t, Bb2, bufS0, nullptr, meta2, nullptr, nullptr, DMID);
    gemm_f16<128, 16, true, 1, 0><<<dim3(DMID / 128, MAXT128), 256, 0, stream>>>(
        bufS0, BW3t, Bb3, bufS1, nullptr, meta2, nullptr, nullptr, DMID);
  }

  // final layer: fp32 scatter to d_out, no relu (128-gran tile map)
  gemm_f16<64, 16, false, 1, 2><<<dim3(1, MAXT128), 256, 0, stream>>>(
      bufS1, BW4t, Bb4, nullptr, out, meta2, nullptr, invperm, DOUT);
}